// Round 14
// baseline (631.399 us; speedup 1.0000x reference)
//
#include <hip/hip_runtime.h>

// GAT 3-layer forward on MI355X — round 14.
// R13 retry: identical design (27 -> 16 dispatches: fused hist, fused scans, cmw fused
// into colsum via last-block pattern, finalize fused into final_reduce, pad-zeroing in
// fscatter). R13's failure was a workspace bug: the 3 last-block counters were given
// 256 BYTES but indexed at +256B/+512B, corrupting rsp and never firing the final
// last-block. Fixed: 768-byte counter allocation (64-int stride per counter).

typedef __attribute__((ext_vector_type(8))) short s8v;
typedef __attribute__((ext_vector_type(4))) float f4v;
typedef __attribute__((ext_vector_type(2))) float f2v;
typedef __attribute__((ext_vector_type(2))) _Float16 h2;
typedef __attribute__((ext_vector_type(4))) _Float16 h4;

__device__ __forceinline__ unsigned short f2bf(float f) {
  unsigned int x = __float_as_uint(f);
  x += 0x7fffu + ((x >> 16) & 1u);          // RTNE
  return (unsigned short)(x >> 16);
}
__device__ __forceinline__ float bf2f(unsigned short u) {
  return __uint_as_float(((unsigned int)u) << 16);
}
__device__ __forceinline__ unsigned short f2h(float f) {
  _Float16 h = (_Float16)f;
  return __builtin_bit_cast(unsigned short, h);
}
__device__ __forceinline__ unsigned char f2fp8(float v) {
  return (unsigned char)(__builtin_amdgcn_cvt_pk_fp8_f32(v, v, 0, false) & 0xff);
}
__device__ __forceinline__ float lrelu(float x) { return fmaxf(x, 0.2f * x); }
__device__ __forceinline__ float elu1(float x) { return x > 0.f ? x : expm1f(x); }

// ---------------- pass 1: per-node degree hist + per-(block,bucket) hist ----------------
__global__ __launch_bounds__(256) void histboth_k(const int* __restrict__ dst, int* __restrict__ counts,
                                                  int* __restrict__ bhist, int E, int NB, int chunk) {
  __shared__ int h[512];
  for (int i = threadIdx.x; i < NB; i += 256) h[i] = 0;
  __syncthreads();
  int e0 = blockIdx.x * chunk;
  int e1 = min(E, e0 + chunk);
  for (int e = e0 + threadIdx.x; e < e1; e += 256) {
    int d = dst[e];
    atomicAdd(&counts[d], 1);
    atomicAdd(&h[d >> 8], 1);
  }
  __syncthreads();
  for (int i = threadIdx.x; i < NB; i += 256)
    bhist[(size_t)i * gridDim.x + blockIdx.x] = h[i];
}

// ---------------- scanA: local exclusive scans of BOTH arrays (1024 elems/block) ----------------
__global__ __launch_bounds__(256) void scanA_k(const int* __restrict__ counts, int* __restrict__ rsp,
                                               int* __restrict__ bsumA, int nb1, int N1,
                                               int* __restrict__ bhist, int* __restrict__ bsumB, int N2) {
  __shared__ int s[256];
  int t = threadIdx.x;
  int b = blockIdx.x;
  bool first = b < nb1;
  int bb = first ? b : b - nb1;
  const int* in = first ? counts : bhist;
  int* out = first ? rsp : bhist;
  int len = first ? N1 : N2;
  int base = bb * 1024 + t * 4;
  int v0 = 0, v1 = 0, v2 = 0, v3 = 0;
  if (first) {
    if (base + 0 < len) v0 = (in[base + 0] + 15) & ~15;
    if (base + 1 < len) v1 = (in[base + 1] + 15) & ~15;
    if (base + 2 < len) v2 = (in[base + 2] + 15) & ~15;
    if (base + 3 < len) v3 = (in[base + 3] + 15) & ~15;
  } else {
    if (base + 0 < len) v0 = in[base + 0];
    if (base + 1 < len) v1 = in[base + 1];
    if (base + 2 < len) v2 = in[base + 2];
    if (base + 3 < len) v3 = in[base + 3];
  }
  s[t] = v0 + v1 + v2 + v3;
  __syncthreads();
  for (int off = 1; off < 256; off <<= 1) {
    int xv = (t >= off) ? s[t - off] : 0;
    __syncthreads();
    s[t] += xv;
    __syncthreads();
  }
  int excl = t ? s[t - 1] : 0;
  if (t == 255) (first ? bsumA : bsumB)[bb] = s[255];
  if (base + 0 < len) { out[base + 0] = excl; excl += v0; }
  if (base + 1 < len) { out[base + 1] = excl; excl += v1; }
  if (base + 2 < len) { out[base + 2] = excl; excl += v2; }
  if (base + 3 < len) { out[base + 3] = excl; }
}

// ---------------- scanB: add prefix-of-blocksums (computed in-block) to both arrays ----------------
__global__ __launch_bounds__(256) void scanB_k(int* __restrict__ rsp, const int* __restrict__ bsumA,
                                               int nb1, int N1,
                                               int* __restrict__ bhist, const int* __restrict__ bsumB, int N2) {
  __shared__ int s[256];
  int t = threadIdx.x;
  int b = blockIdx.x;
  bool first = b < nb1;
  int k = first ? b : b - nb1;
  int* arr = first ? rsp : bhist;
  const int* bs = first ? bsumA : bsumB;
  int len = first ? N1 : N2;
  int acc = 0;
  for (int i = t; i < k; i += 256) acc += bs[i];
  s[t] = acc;
  __syncthreads();
  for (int off = 128; off > 0; off >>= 1) {
    if (t < off) s[t] += s[t + off];
    __syncthreads();
  }
  int pref = s[0];
  if (pref == 0) return;
  int base = k * 1024;
  for (int i = t; i < 1024; i += 256) {
    int idx = base + i;
    if (idx < len) arr[idx] += pref;
  }
}

// ---------------- pass 2: scatter edges into private (block,bucket) segments ----------------
__global__ __launch_bounds__(256) void bscatter_k(const int* __restrict__ src, const int* __restrict__ dst,
                                                  const int* __restrict__ seg, int2* __restrict__ ebuf,
                                                  int E, int NB, int chunk) {
  __shared__ int cur[512];
  for (int i = threadIdx.x; i < NB; i += 256)
    cur[i] = seg[(size_t)i * gridDim.x + blockIdx.x];
  __syncthreads();
  int e0 = blockIdx.x * chunk;
  int e1 = min(E, e0 + chunk);
  for (int e = e0 + threadIdx.x; e < e1; e += 256) {
    int d = dst[e];
    int pos = atomicAdd(&cur[d >> 8], 1);
    int2 v; v.x = src[e]; v.y = d;
    ebuf[pos] = v;
  }
}

// ---------------- pass 3: per-bucket final scatter + pad zeroing ----------------
__global__ __launch_bounds__(256) void fscatter_k(const int2* __restrict__ ebuf, const int* __restrict__ seg,
                                                  const int* __restrict__ rsp, const int* __restrict__ counts,
                                                  int* __restrict__ csr_src,
                                                  int E, int NB, int P2B, int Nn) {
  __shared__ int cur[256];
  int b = blockIdx.x;
  int node0 = b << 8;
  int node = node0 + threadIdx.x;
  if (node < Nn) cur[threadIdx.x] = rsp[node];
  __syncthreads();
  int bstart = seg[(size_t)b * P2B];
  int bend = (b + 1 < NB) ? seg[(size_t)(b + 1) * P2B] : E;
  for (int e = bstart + threadIdx.x; e < bend; e += 256) {
    int2 sd = ebuf[e];
    int pos = atomicAdd(&cur[sd.y - node0], 1);
    csr_src[pos] = sd.x;
  }
  __syncthreads();
  if (node < Nn) {
    int end = rsp[node] + ((counts[node] + 15) & ~15);
    for (int q = cur[threadIdx.x]; q < end; q++) csr_src[q] = 0;   // pads: node 0, alpha 0
  }
}

// ---------------- fused weight pack (all 3 layers, one launch) ----------------
__device__ __forceinline__ void pack_one(const float* W, const float* al, const float* ar,
                                         const float* resW, unsigned short* out,
                                         int K, int M, int BF, int H, int RES0, int t) {
  int c = t / K, k = t - c * K;
  float v = 0.f;
  if (c < BF) {
    v = W[k * BF + c];
  } else if (c < BF + H) {
    int h = c - BF;
    float s = 0.f;
    for (int d = 0; d < 32; d++) s += W[k * BF + h * 32 + d] * al[h * 32 + d];
    v = s;
  } else if (c < BF + 2 * H) {
    int h = c - BF - H;
    float s = 0.f;
    for (int d = 0; d < 32; d++) s += W[k * BF + h * 32 + d] * ar[h * 32 + d];
    v = s;
  } else if (c >= RES0) {
    v = resW[k * (M - RES0) + (c - RES0)];
  }
  unsigned short hi = f2bf(v);
  out[c * K + k] = hi;
  out[M * K + c * K + k] = f2bf(v - bf2f(hi));
}

__global__ __launch_bounds__(256) void fill_all(const float* __restrict__ W0, const float* __restrict__ al0,
                                                const float* __restrict__ ar0,
                                                const float* __restrict__ W1, const float* __restrict__ al1,
                                                const float* __restrict__ ar1, const float* __restrict__ resW1,
                                                const float* __restrict__ W2, const float* __restrict__ al2,
                                                const float* __restrict__ ar2, const float* __restrict__ resW2,
                                                unsigned short* __restrict__ w0t, unsigned short* __restrict__ w1t,
                                                unsigned short* __restrict__ w2t) {
  const int n0 = 144 * 64, n1 = 272 * 128, n2 = 80 * 128;
  int t = blockIdx.x * 256 + threadIdx.x;
  if (t < n0) {
    pack_one(W0, al0, ar0, nullptr, w0t, 64, 144, 128, 4, 144, t);
  } else if (t < n0 + n1) {
    pack_one(W1, al1, ar1, resW1, w1t, 128, 272, 128, 4, 144, t - n0);
  } else if (t < n0 + n1 + n2) {
    pack_one(W2, al2, ar2, resW2, w2t, 128, 80, 32, 1, 48, t - n0 - n1);
  }
}

// ---------------- GEMM: A[N,K] @ Bt[M,K](bf16 hi+lo); epilogue: -cmw, route cols ----------------
template <int K, int M, int R, int BF, int H, int RES0, bool AF32, bool CMW>
__global__ __launch_bounds__(256) void gemm_bf16(const void* __restrict__ Av,
                                                 const unsigned short* __restrict__ Bt,
                                                 const float* __restrict__ cmw,
                                                 unsigned char* __restrict__ feat8,
                                                 float* __restrict__ el, float* __restrict__ er,
                                                 unsigned short* __restrict__ resh, int nRowTiles) {
  int wv = (int)((blockIdx.x * blockDim.x + threadIdx.x) >> 6);
  int tile0 = wv * R;
  if (tile0 >= nRowTiles) return;
  int lane = threadIdx.x & 63;
  int r = lane & 15, q = lane >> 4;
  s8v afrag[R][K / 32];
#pragma unroll
  for (int rr = 0; rr < R; rr++) {
    if constexpr (AF32) {
      const float* arow = (const float*)Av + (size_t)((tile0 + rr) * 16 + r) * K + q * 8;
#pragma unroll
      for (int kk = 0; kk < K / 32; kk++) {
        s8v v;
#pragma unroll
        for (int j = 0; j < 8; j++) v[j] = (short)f2bf(arow[kk * 32 + j]);
        afrag[rr][kk] = v;
      }
    } else {
      const unsigned short* arow = (const unsigned short*)Av + (size_t)((tile0 + rr) * 16 + r) * K + q * 8;
#pragma unroll
      for (int kk = 0; kk < K / 32; kk++) afrag[rr][kk] = *(const s8v*)(arow + kk * 32);
    }
  }
#pragma unroll
  for (int ct = 0; ct < M / 16; ct++) {
    const unsigned short* brow = Bt + (size_t)(ct * 16 + r) * K + q * 8;
    s8v bhi[K / 32], blo[K / 32];
#pragma unroll
    for (int kk = 0; kk < K / 32; kk++) {
      bhi[kk] = *(const s8v*)(brow + kk * 32);
      blo[kk] = *(const s8v*)(brow + (size_t)M * K + kk * 32);
    }
    int col = ct * 16 + r;
    float cmwv = 0.f;
    if constexpr (CMW) cmwv = cmw[col];
#pragma unroll
    for (int rr = 0; rr < R; rr++) {
      f4v acc = {0.f, 0.f, 0.f, 0.f};
#pragma unroll
      for (int kk = 0; kk < K / 32; kk++) {
        acc = __builtin_amdgcn_mfma_f32_16x16x32_bf16(afrag[rr][kk], bhi[kk], acc, 0, 0, 0);
        acc = __builtin_amdgcn_mfma_f32_16x16x32_bf16(afrag[rr][kk], blo[kk], acc, 0, 0, 0);
      }
      int row0 = (tile0 + rr) * 16 + q * 4;
#pragma unroll
      for (int i = 0; i < 4; i++) {
        float v = acc[i] - cmwv;
        size_t row = (size_t)(row0 + i);
        if (col < BF) {
          feat8[row * BF + col] = f2fp8(v);
        } else if (col < BF + H) {
          el[row * H + (col - BF)] = v;
        } else if (col < BF + 2 * H) {
          er[row * H + (col - BF - H)] = v;
        } else if (RES0 < M && col >= RES0) {
          resh[row * (M - RES0) + (col - RES0)] = f2h(v);
        }
      }
    }
  }
}

// ---------------- fused single-pass aggregation H=4 (fp8 feat table) ----------------
template <int MODE>
__global__ __launch_bounds__(256) void aggregate4(const unsigned char* __restrict__ feat8,
                                                  const float* __restrict__ el4,
                                                  const float* __restrict__ er4,
                                                  const int* __restrict__ csr_src,
                                                  const int* __restrict__ rsp,
                                                  const int* __restrict__ counts,
                                                  const unsigned short* __restrict__ resh,
                                                  unsigned short* __restrict__ vbf,
                                                  float* __restrict__ rnrm, int Nn) {
  int n = (int)((blockIdx.x * blockDim.x + threadIdx.x) >> 6);
  if (n >= Nn) return;
  int lane = threadIdx.x & 63;
  int start = __builtin_amdgcn_readfirstlane(rsp[n]);
  int deg = __builtin_amdgcn_readfirstlane(counts[n]);
  int chunks = (deg + 15) >> 4;
  int slot = lane >> 2, h = lane & 3;
  float ern = er4[(size_t)n * 4 + h];
  int hl = lane >> 4;                        // head of lane's dims (dims 2l..2l+1)
  unsigned dby = (unsigned)lane << 1;        // byte offset into 128B fp8 row
  float a0 = 0.f, a1 = 0.f, dsum = 0.f;
  for (int c = 0; c < chunks; c++) {
    const int* csp = csr_src + start + (c << 4);
    // phase A: one (edge,head) per lane
    int sA = csp[slot];
    float exv = 0.f;
    if (((c << 4) + slot) < deg) {
      float e = el4[(size_t)sA * 4 + h] + ern;
      exv = __expf(fmaxf(e, 0.2f * e));
    }
    dsum += exv;
    // phase B: batch all 16 csr reads first (independent loads in flight)
    int sj[16];
#pragma unroll
    for (int j = 0; j < 16; j++) sj[j] = csp[j];
#pragma unroll
    for (int j = 0; j < 16; j++) {
      float aw = __shfl(exv, (j << 2) | hl);
      unsigned short u = *(const unsigned short*)(feat8 + (((unsigned)sj[j] << 7) + dby));
      f2v fv = __builtin_amdgcn_cvt_pk_f32_fp8((int)u, false);
      a0 = fmaf(fv[0], aw, a0);
      a1 = fmaf(fv[1], aw, a1);
    }
  }
  // per-head denominator totals: after butterfly, lane l holds head (l&3) total
#pragma unroll
  for (int off = 4; off < 64; off <<= 1) dsum += __shfl_xor(dsum, off);
  float inv = dsum > 0.f ? 1.f / dsum : 0.f;
  float invh = __shfl(inv, hl);
  float v0, v1;
  if (MODE == 1) {
    h2 rr = *(const h2*)(resh + (size_t)n * 128 + lane * 2);
    v0 = elu1(elu1(a0 * invh + (float)rr[0]));
    v1 = elu1(elu1(a1 * invh + (float)rr[1]));
  } else {
    v0 = elu1(a0 * invh);
    v1 = elu1(a1 * invh);
  }
  float ss = v0 * v0 + v1 * v1;
#pragma unroll
  for (int off = 1; off < 64; off <<= 1) ss += __shfl_xor(ss, off);
  float rn = sqrtf(1e-6f + ss);
  float ri = 1.f / rn;
  unsigned int pk = (unsigned int)f2bf(v0 * ri) | ((unsigned int)f2bf(v1 * ri) << 16);
  *(unsigned int*)((char*)vbf + ((size_t)n << 8) + (lane << 2)) = pk;
  if (lane == 0) rnrm[n] = rn;
}

// ---------------- fused single-pass aggregation H=1 (layer 2, fp8 table) ----------------
__global__ __launch_bounds__(256) void aggregate1(const unsigned char* __restrict__ feat8,
                                                  const float* __restrict__ el1,
                                                  const float* __restrict__ er1,
                                                  const int* __restrict__ csr_src,
                                                  const int* __restrict__ rsp,
                                                  const int* __restrict__ counts,
                                                  const unsigned short* __restrict__ res2h,
                                                  float* __restrict__ out2, int Nn) {
  int n = (int)((blockIdx.x * blockDim.x + threadIdx.x) >> 6);
  if (n >= Nn) return;
  int lane = threadIdx.x & 63;
  int start = __builtin_amdgcn_readfirstlane(rsp[n]);
  int deg = __builtin_amdgcn_readfirstlane(counts[n]);
  int chunks = (deg + 15) >> 4;
  int l16 = lane & 15;
  float ern = er1[n];
  int g = lane >> 3;                          // 8 edge groups (2 edges each per chunk)
  unsigned dofs4 = (unsigned)(lane & 7) << 2; // byte offset into 32B fp8 row
  f4v acc = {0.f, 0.f, 0.f, 0.f};
  float dsum = 0.f;
  for (int c = 0; c < chunks; c++) {
    const int* csp = csr_src + start + (c << 4);
    int sA = csp[l16];
    float exv = 0.f;
    if (((c << 4) + l16) < deg) exv = __expf(lrelu(el1[sA] + ern));
    dsum += exv;
#pragma unroll
    for (int t = 0; t < 2; t++) {
      int j = (t << 3) + g;
      int sj = __shfl(sA, j);
      float aw = __shfl(exv, j);
      unsigned int u = *(const unsigned int*)(feat8 + (((unsigned)sj << 5) + dofs4));
      f2v fa = __builtin_amdgcn_cvt_pk_f32_fp8((int)u, false);
      f2v fb = __builtin_amdgcn_cvt_pk_f32_fp8((int)u, true);
      acc[0] = fmaf(fa[0], aw, acc[0]);
      acc[1] = fmaf(fa[1], aw, acc[1]);
      acc[2] = fmaf(fb[0], aw, acc[2]);
      acc[3] = fmaf(fb[1], aw, acc[3]);
    }
  }
#pragma unroll
  for (int off = 1; off < 16; off <<= 1) dsum += __shfl_xor(dsum, off);
  float inv = dsum > 0.f ? 1.f / dsum : 0.f;
#pragma unroll
  for (int off = 8; off < 64; off <<= 1) {
    acc[0] += __shfl_xor(acc[0], off);
    acc[1] += __shfl_xor(acc[1], off);
    acc[2] += __shfl_xor(acc[2], off);
    acc[3] += __shfl_xor(acc[3], off);
  }
  if (lane < 8) {
    h4 rr = *(const h4*)(res2h + (size_t)n * 32 + (lane << 2));
    float4 o;
    o.x = acc[0] * inv + (float)rr[0];
    o.y = acc[1] * inv + (float)rr[1];
    o.z = acc[2] * inv + (float)rr[2];
    o.w = acc[3] * inv + (float)rr[3];
    *(float4*)(out2 + (size_t)n * 32 + (lane << 2)) = o;
  }
}

// ---------------- colsum + cmw fused (last-block pattern) ----------------
__global__ __launch_bounds__(256) void colsum_cmw_k(const unsigned short* __restrict__ vbf,
                                                    const float* __restrict__ rnrm,
                                                    float* __restrict__ colsum,
                                                    const unsigned short* __restrict__ wt,
                                                    float* __restrict__ cmw, int M, float invN,
                                                    int Nn, int* __restrict__ counter) {
  __shared__ float ls[256];
  int tid = threadIdx.x;
  int c = tid & 127, rsub = tid >> 7;
  float cs = 0.f;
  for (int r = blockIdx.x * 2 + rsub; r < Nn; r += gridDim.x * 2)
    cs += bf2f(vbf[(size_t)r * 128 + c]) * rnrm[r];
  ls[tid] = cs;
  __syncthreads();
  if (tid < 128) atomicAdd(&colsum[tid], ls[tid] + ls[tid + 128]);
  __threadfence();
  __shared__ int lastFlag;
  if (tid == 0) lastFlag = (atomicAdd(counter, 1) == (int)gridDim.x - 1) ? 1 : 0;
  __syncthreads();
  if (!lastFlag) return;
  __shared__ float csf[128];
  if (tid < 128)
    csf[tid] = __hip_atomic_load(&colsum[tid], __ATOMIC_RELAXED, __HIP_MEMORY_SCOPE_AGENT);
  __syncthreads();
  for (int col = tid; col < M; col += 256) {
    float s = 0.f;
    for (int k = 0; k < 128; k++)
      s += csf[k] * (bf2f(wt[col * 128 + k]) + bf2f(wt[(size_t)M * 128 + col * 128 + k]));
    cmw[col] = s * invN;
  }
}

// ---------------- final: mean over nodes of out2, fused finalize (last block) ----------------
__global__ __launch_bounds__(256) void final_reduce(const float* __restrict__ out2,
                                                    float* __restrict__ outsum, int Nn,
                                                    float* __restrict__ out, float invN,
                                                    int* __restrict__ counter) {
  __shared__ float ls[32];
  if (threadIdx.x < 32) ls[threadIdx.x] = 0.f;
  __syncthreads();
  int d = threadIdx.x & 31, rl = threadIdx.x >> 5;
  float acc = 0.f;
  for (int n = blockIdx.x * 8 + rl; n < Nn; n += gridDim.x * 8)
    acc += out2[(size_t)n * 32 + d];
  atomicAdd(&ls[d], acc);
  __syncthreads();
  if (threadIdx.x < 32) atomicAdd(&outsum[threadIdx.x], ls[threadIdx.x]);
  __threadfence();
  __shared__ int lastFlag;
  if (threadIdx.x == 0) lastFlag = (atomicAdd(counter, 1) == (int)gridDim.x - 1) ? 1 : 0;
  __syncthreads();
  if (lastFlag && threadIdx.x < 32)
    out[threadIdx.x] =
        __hip_atomic_load(&outsum[threadIdx.x], __ATOMIC_RELAXED, __HIP_MEMORY_SCOPE_AGENT) * invN;
}

// ---------------- launcher ----------------
extern "C" void kernel_launch(void* const* d_in, const int* in_sizes, int n_in,
                              void* d_out, int out_size, void* d_ws, size_t ws_size,
                              hipStream_t stream) {
  const float* x     = (const float*)d_in[0];
  const int*   src   = (const int*)d_in[1];
  const int*   dst   = (const int*)d_in[2];
  const float* W0    = (const float*)d_in[3];
  const float* al0   = (const float*)d_in[4];
  const float* ar0   = (const float*)d_in[5];
  const float* W1    = (const float*)d_in[6];
  const float* al1   = (const float*)d_in[7];
  const float* ar1   = (const float*)d_in[8];
  const float* resW1 = (const float*)d_in[9];
  const float* W2    = (const float*)d_in[10];
  const float* al2   = (const float*)d_in[11];
  const float* ar2   = (const float*)d_in[12];
  const float* resW2 = (const float*)d_in[13];
  const int N = in_sizes[0] / 64;   // 100000
  const int E = in_sizes[1];        // 1600000
  const float invN = 1.f / (float)N;
  const int Emax = E + 15 * N + 1024;   // upper bound on padded slot count + margin
  const int NB = (N + 255) >> 8;        // dst buckets of 256 nodes (391)
  const int P2B = 256;                  // pass-2 block count
  const int chunk = (E + P2B - 1) / P2B;
  const int segN = NB * P2B;            // bucket-major segment table length
  const int nb1 = (N + 1023) / 1024;    // scan blocks for rsp
  const int nb2 = (segN + 1023) / 1024; // scan blocks for seg table

  char* p = (char*)d_ws;
  auto alloc = [&](size_t bytes) { char* r = p; p += (bytes + 255) & ~(size_t)255; return r; };

  // zero-initialized region
  char* zbase = p;
  int*   counts  = (int*)alloc((size_t)4 * N);
  float* colsumA = (float*)alloc(512);
  float* colsumB = (float*)alloc(512);
  float* outsum  = (float*)alloc(128);
  int*   cntA    = (int*)alloc(768);    // 3 last-block counters, 64-int (256B) stride each
  int*   cntB    = cntA + 64;
  int*   cntF    = cntA + 128;
  size_t zbytes = (size_t)(p - zbase);

  int* rsp   = (int*)alloc((size_t)4 * N);      // padded row starts
  int* bsumA = (int*)alloc(512);
  int* bsumB = (int*)alloc(512);
  int* bhist = (int*)alloc((size_t)4 * segN);   // per-(bucket,block) counts -> seg (scanned in place)
  int2* ebuf = (int2*)alloc((size_t)8 * E);     // bucketed {src,dst}
  int* csr_src = (int*)alloc((size_t)4 * Emax); // pads zeroed by fscatter
  unsigned char*  feat8 = (unsigned char*)alloc((size_t)N * 128);     // fp8 gather table
  unsigned short* vbf   = (unsigned short*)alloc((size_t)2 * N * 128);
  unsigned short* resh  = (unsigned short*)alloc((size_t)2 * N * 128);  // f16 residuals
  unsigned short* w0t = (unsigned short*)alloc((size_t)2 * 2 * 144 * 64);
  unsigned short* w1t = (unsigned short*)alloc((size_t)2 * 2 * 272 * 128);
  unsigned short* w2t = (unsigned short*)alloc((size_t)2 * 2 * 80 * 128);
  float* el4  = (float*)alloc((size_t)16 * N);
  float* er4  = (float*)alloc((size_t)16 * N);
  float* rnrm = (float*)alloc((size_t)4 * N);
  float* cmw1 = (float*)alloc(4 * 272);
  float* cmw2 = (float*)alloc(4 * 80);
  float* out2 = (float*)alloc((size_t)4 * N * 32);   // layer-2 output [N][32]

  hipMemsetAsync(zbase, 0, zbytes, stream);

  // CSR build: fused hist (node degrees + bucket segments), fused scans, 2-pass scatter
  histboth_k<<<P2B, 256, 0, stream>>>(dst, counts, bhist, E, NB, chunk);
  scanA_k<<<nb1 + nb2, 256, 0, stream>>>(counts, rsp, bsumA, nb1, N, bhist, bsumB, segN);
  scanB_k<<<nb1 + nb2, 256, 0, stream>>>(rsp, bsumA, nb1, N, bhist, bsumB, segN);
  bscatter_k<<<P2B, 256, 0, stream>>>(src, dst, bhist, ebuf, E, NB, chunk);
  fscatter_k<<<NB, 256, 0, stream>>>(ebuf, bhist, rsp, counts, csr_src, E, NB, P2B, N);

  // weights: [W | W@al | W@ar | pad | resW] transposed, bf16 hi+lo — one launch
  const int packTot = 144 * 64 + 272 * 128 + 80 * 128;
  fill_all<<<(packTot + 255) / 256, 256, 0, stream>>>(W0, al0, ar0, W1, al1, ar1, resW1,
                                                      W2, al2, ar2, resW2, w0t, w1t, w2t);

  const int rowTiles = N / 16;                  // 6250, divisible by R=5
  const int gblocks = (rowTiles / 5 + 3) / 4;   // 1250 waves, 4/block
  const int aggblocks = (N + 3) / 4;            // wave per node

  // Layer 0 (A = x fp32, no colmean fold)
  gemm_bf16<64, 144, 5, 128, 4, 144, true, false><<<gblocks, 256, 0, stream>>>(
      x, w0t, nullptr, feat8, el4, er4, nullptr, rowTiles);
  aggregate4<0><<<aggblocks, 256, 0, stream>>>(feat8, el4, er4, csr_src, rsp, counts, nullptr, vbf, rnrm, N);
  colsum_cmw_k<<<512, 256, 0, stream>>>(vbf, rnrm, colsumA, w1t, cmw1, 272, invN, N, cntA);

  // Layer 1 (A = vbf, colmean folded via cmw1)
  gemm_bf16<128, 272, 5, 128, 4, 144, false, true><<<gblocks, 256, 0, stream>>>(
      vbf, w1t, cmw1, feat8, el4, er4, resh, rowTiles);
  aggregate4<1><<<aggblocks, 256, 0, stream>>>(feat8, el4, er4, csr_src, rsp, counts, resh, vbf, rnrm, N);
  colsum_cmw_k<<<512, 256, 0, stream>>>(vbf, rnrm, colsumB, w2t, cmw2, 80, invN, N, cntB);

  // Layer 2 (A = vbf, colmean folded via cmw2)
  gemm_bf16<128, 80, 5, 32, 1, 48, false, true><<<gblocks, 256, 0, stream>>>(
      vbf, w2t, cmw2, feat8, el4, er4, resh, rowTiles);
  aggregate1<<<aggblocks, 256, 0, stream>>>(feat8, el4, er4, csr_src, rsp, counts, resh, out2, N);
  final_reduce<<<512, 256, 0, stream>>>(out2, outsum, N, (float*)d_out, invN, cntF);
}